// Round 3
// baseline (796.855 us; speedup 1.0000x reference)
//
#include <hip/hip_runtime.h>
#include <hip/hip_bf16.h>

#define Bb 4
#define Nn 4096
#define C1 320
#define C2 256
#define Hh 5
#define HD 64
#define Mm (Bb*Nn)   // 16384

using bf16 = __hip_bfloat16;
typedef __attribute__((ext_vector_type(8))) short  short8;   // 8 bf16 = one MFMA A/B frag
typedef __attribute__((ext_vector_type(4))) short  short4_;
typedef __attribute__((ext_vector_type(4))) float  f32x4;    // 16x16 MFMA C/D frag
typedef __attribute__((ext_vector_type(16))) float f32x16;   // 32x32 MFMA C/D frag

__device__ __forceinline__ short f2s(float f) {
    bf16 h = __float2bfloat16(f);
    short s;
    __builtin_memcpy(&s, &h, 2);
    return s;
}

__device__ __forceinline__ float fexp2(float x) {
#if __has_builtin(__builtin_amdgcn_exp2f)
    return __builtin_amdgcn_exp2f(x);
#else
    return exp2f(x);
#endif
}

// XOR-swizzled LDS tile addressing: 64-elem rows, 8 blocks of 8 bf16 (16B).
// physical elem offset of (row, logical block bb) = row*64 + (bb ^ (row&7))*8
__device__ __forceinline__ int swz(int row, int bb) {
    return row * 64 + ((bb ^ (row & 7)) << 3);
}

// pack two f32 -> one dword of 2 bf16 (src0 -> low half)
__device__ __forceinline__ unsigned cvtpk(float lo, float hi) {
    unsigned r;
    asm("v_cvt_pk_bf16_f32 %0, %1, %2" : "=v"(r) : "v"(lo), "v"(hi));
    return r;
}

// swap: a[lanes 32..63] <- b[lanes 0..31]; b[lanes 0..31] <- a[lanes 32..63]
__device__ __forceinline__ void plswap(unsigned &a, unsigned &b) {
#if __has_builtin(__builtin_amdgcn_permlane32_swap)
    auto r = __builtin_amdgcn_permlane32_swap(a, b, false, false);
    a = r[0]; b = r[1];
#else
    asm("v_permlane32_swap_b32 %0, %1" : "+v"(a), "+v"(b));
#endif
}

__device__ __forceinline__ short8 mk8(unsigned d0, unsigned d1, unsigned d2, unsigned d3) {
    union { unsigned u[4]; short8 s; } u;
    u.u[0] = d0; u.u[1] = d1; u.u[2] = d2; u.u[3] = d3;
    return u.s;
}

// ---------------- fp32 -> bf16 convert, all 8 tensors in one launch ----------------
struct CvtArgs {
    const float* s[8];
    bf16* d[8];
    int off[9];   // cumulative offsets, off[8] = total
};

__global__ void cvt_all(CvtArgs a) {
    int i = (blockIdx.x * blockDim.x + threadIdx.x) * 4;
    if (i >= a.off[8]) return;
    int seg = 0;
    #pragma unroll
    for (int k = 1; k < 8; ++k) seg += (i >= a.off[k]);
    int j = i - a.off[seg];
    float4 v = *(const float4*)(a.s[seg] + j);
    short4_ o = { f2s(v.x), f2s(v.y), f2s(v.z), f2s(v.w) };
    *(short4_*)(a.d[seg] + j) = o;
}

// ---------------- generic GEMM: C[M,n0..] = A[M,K] x W[Nout,K]^T ----------------
// mode 0: store bf16*oscale to O1[row*320+col]
// mode 1: col<320 -> O1 (K part, [M,320]); col>=320 -> O2 = V transposed [B,H,64,N]
// mode 2: fp32 out Of[row*640 + ooff + col] + bias[col]
__global__ __launch_bounds__(256) void gemm_bt(
    const bf16* __restrict__ A, const bf16* __restrict__ W,
    int K, int mode, float oscale,
    bf16* __restrict__ O1, bf16* __restrict__ O2,
    const float* __restrict__ bias, float* __restrict__ Of, int ooff)
{
    __shared__ bf16 la[64 * 64];
    __shared__ bf16 lw[64 * 64];
    const int m0 = blockIdx.x * 64, n0 = blockIdx.y * 64;
    const int t = threadIdx.x;
    const int wave = t >> 6, lane = t & 63, l16 = lane & 15, quad = lane >> 4;
    const int sr = t >> 3, sb = t & 7;

    f32x4 acc[4] = {{0.f,0.f,0.f,0.f},{0.f,0.f,0.f,0.f},{0.f,0.f,0.f,0.f},{0.f,0.f,0.f,0.f}};

    const int nk = K >> 6;
    // register prefetch of first k-tile
    short8 ra0 = *(const short8*)(A + (size_t)(m0 + sr) * K + sb * 8);
    short8 ra1 = *(const short8*)(A + (size_t)(m0 + sr + 32) * K + sb * 8);
    short8 rw0 = *(const short8*)(W + (size_t)(n0 + sr) * K + sb * 8);
    short8 rw1 = *(const short8*)(W + (size_t)(n0 + sr + 32) * K + sb * 8);

    for (int kt = 0; kt < nk; ++kt) {
        __syncthreads();
        *(short8*)&la[swz(sr, sb)]      = ra0;
        *(short8*)&la[swz(sr + 32, sb)] = ra1;
        *(short8*)&lw[swz(sr, sb)]      = rw0;
        *(short8*)&lw[swz(sr + 32, sb)] = rw1;
        __syncthreads();
        if (kt + 1 < nk) {
            const int k0 = (kt + 1) * 64;
            ra0 = *(const short8*)(A + (size_t)(m0 + sr) * K + k0 + sb * 8);
            ra1 = *(const short8*)(A + (size_t)(m0 + sr + 32) * K + k0 + sb * 8);
            rw0 = *(const short8*)(W + (size_t)(n0 + sr) * K + k0 + sb * 8);
            rw1 = *(const short8*)(W + (size_t)(n0 + sr + 32) * K + k0 + sb * 8);
        }
        const int arow = wave * 16 + l16;
        short8 a0 = *(const short8*)&la[swz(arow, quad)];
        short8 a1 = *(const short8*)&la[swz(arow, quad + 4)];
        #pragma unroll
        for (int nt = 0; nt < 4; ++nt) {
            const int brow = nt * 16 + l16;
            short8 b0 = *(const short8*)&lw[swz(brow, quad)];
            short8 b1 = *(const short8*)&lw[swz(brow, quad + 4)];
            acc[nt] = __builtin_amdgcn_mfma_f32_16x16x32_bf16(a0, b0, acc[nt], 0, 0, 0);
            acc[nt] = __builtin_amdgcn_mfma_f32_16x16x32_bf16(a1, b1, acc[nt], 0, 0, 0);
        }
    }

    const int mrow = m0 + wave * 16 + quad * 4;
    if (mode == 2) {
        #pragma unroll
        for (int nt = 0; nt < 4; ++nt) {
            int col = n0 + nt * 16 + l16;
            float bv = bias[col];
            #pragma unroll
            for (int r = 0; r < 4; ++r)
                Of[(size_t)(mrow + r) * 640 + ooff + col] = acc[nt][r] + bv;
        }
    } else if (mode == 0 || n0 < C1) {
        #pragma unroll
        for (int nt = 0; nt < 4; ++nt) {
            int col = n0 + nt * 16 + l16;
            #pragma unroll
            for (int r = 0; r < 4; ++r)
                O1[(size_t)(mrow + r) * C1 + col] = __float2bfloat16(acc[nt][r] * oscale);
        }
    } else {
        // V part: write transposed [B,H,64,N]
        #pragma unroll
        for (int nt = 0; nt < 4; ++nt) {
            int col = n0 + nt * 16 + l16 - C1;
            int h = col >> 6, d = col & 63;
            #pragma unroll
            for (int r = 0; r < 4; ++r) {
                int m = mrow + r;
                int b = m >> 12, n = m & (Nn - 1);
                O2[((size_t)(b * Hh + h) * 64 + d) * Nn + n] = __float2bfloat16(acc[nt][r]);
            }
        }
    }
}

// ---------------- flash attention, both branches in one launch ----------------
// Split-K x2, 8-wave blocks (512 thr): waves 0-3 = 4 q-waves x 64 q on k-half 0,
// waves 4-7 same q on k-half 1. Doubles wave count (5120 = 4/SIMD) for pipe
// overlap (QK-MFMA / exp / PV-MFMA serialize within a wave; more waves hide it).
// Per-wave structure identical to the proven R1 kernel: swapped QK^T 32x32 MFMA
// (lane holds P-row slice: q=lane&31, k=(r&3)+8*(r>>2)+4*hi), in-register
// P->bf16 via cvt_pk+permlane32_swap, VALU lsum, fixed m=0 softmax.
// Shared 16KB LDS tiles: lk rows 0-31 = half0's 32 k-rows, rows 32-63 = half1's;
// lv cols 0-31 = half0's k, 32-63 = half1's. Staged by all 512 threads, one
// short8 each for K and V, register-prefetched one k-step ahead, 2 barriers/kt.
// Partial (o, lsum) of k-half 1 combined into k-half 0 via LDS at the end.
__global__ __launch_bounds__(512, 4) void flash_kernel(
    const bf16* __restrict__ Q1, const bf16* __restrict__ K1,
    const bf16* __restrict__ V1, bf16* __restrict__ Y1,
    const bf16* __restrict__ Q2, const bf16* __restrict__ K2,
    const bf16* __restrict__ V2, bf16* __restrict__ Y2)
{
    __shared__ bf16 lk[64 * 64];        // K tile [k(2 halves)][d], swizzled
    __shared__ bf16 lv[64 * 64];        // V tile [d][k(2 halves)], swizzled
    const int qt = blockIdx.x, h = blockIdx.y, z = blockIdx.z;
    const int b = z & 3, branch = z >> 2;
    const bf16* Q  = branch ? Q2 : Q1;
    const bf16* Km = branch ? K2 : K1;
    const bf16* Vt = branch ? V2 : V1;
    bf16*       Yo = branch ? Y2 : Y1;

    const int t = threadIdx.x;
    const int wave = t >> 6, lane = t & 63;
    const int l32 = lane & 31, hi = lane >> 5;
    const int qw = wave & 3, khalf = wave >> 2;
    const int sr = t >> 3, sb = t & 7;          // sr 0-63, sb 0-7 (512 threads)

    const int qrow0 = qt * 256 + qw * 64;       // this wave's 64 q rows

    // Q B-frags for the whole loop: [qb][ksd] -> Q[qrow0+qb*32+l32][ksd*16+hi*8 ..+7]
    short8 qf[2][4];
    #pragma unroll
    for (int qb = 0; qb < 2; ++qb) {
        const bf16* qptr = Q + (size_t)(b * Nn + qrow0 + qb * 32 + l32) * C1 + h * HD + hi * 8;
        #pragma unroll
        for (int ksd = 0; ksd < 4; ++ksd)
            qf[qb][ksd] = *(const short8*)(qptr + ksd * 16);
    }

    f32x16 o[2][2];                    // [qb][db] PV accumulators (this k-half's partial)
    #pragma unroll
    for (int qb = 0; qb < 2; ++qb)
        #pragma unroll
        for (int db = 0; db < 2; ++db)
            o[qb][db] = (f32x16){0.f,0.f,0.f,0.f,0.f,0.f,0.f,0.f,0.f,0.f,0.f,0.f,0.f,0.f,0.f,0.f};
    float lsum[2] = {0.f, 0.f};

    const bf16* Kbase = Km + (size_t)b * Nn * C1 + h * HD;
    const bf16* Vbase = Vt + (size_t)(b * Hh + h) * 64 * Nn;

    // staging pointers: K rows 0-31 <- half0 rows kt*32+(sr&31); rows 32-63 <- half1.
    // V cols: sb<4 -> half0 k, sb>=4 -> half1 k.
    const bf16* kp = Kbase + (size_t)((sr >> 5) * 2048 + (sr & 31)) * C1 + sb * 8;
    const bf16* vp = Vbase + (size_t)sr * Nn + (sb >> 2) * 2048 + (sb & 3) * 8;
    short8 rk = *(const short8*)kp;
    short8 rv = *(const short8*)vp;

    const int NT = 2048 / 32;                   // 64 k-steps of 32 per half
    for (int kt = 0; kt < NT; ++kt) {
        __syncthreads();                        // prior iter's readers done
        *(short8*)&lk[swz(sr, sb)] = rk;
        *(short8*)&lv[swz(sr, sb)] = rv;
        __syncthreads();
        if (kt + 1 < NT) {                      // prefetch next step; overlaps compute
            kp += 32 * C1; vp += 32;
            rk = *(const short8*)kp;
            rv = *(const short8*)vp;
        }

        // K a-frags for this wave's k-half (rows khalf*32 + l32), reused by both qb
        short8 ka[4];
        #pragma unroll
        for (int ksd = 0; ksd < 4; ++ksd)
            ka[ksd] = *(const short8*)&lk[swz(khalf * 32 + l32, ksd * 2 + hi)];

        short8 pa[2][2];   // [qb][ks] PV A-frags, built fully in-register
        #pragma unroll
        for (int qb = 0; qb < 2; ++qb) {
            f32x16 s = (f32x16){0.f,0.f,0.f,0.f,0.f,0.f,0.f,0.f,0.f,0.f,0.f,0.f,0.f,0.f,0.f,0.f};
            #pragma unroll
            for (int ksd = 0; ksd < 4; ++ksd)
                s = __builtin_amdgcn_mfma_f32_32x32x16_bf16(ka[ksd], qf[qb][ksd], s, 0, 0, 0);
            // p[r] = P[q = l32][k = (r&3) + 8*(r>>2) + 4*hi] (within this k-step)
            float p[16];
            #pragma unroll
            for (int r = 0; r < 16; ++r) p[r] = fexp2(s[r]);
            lsum[qb] += (((p[0]+p[1])+(p[2]+p[3])) + ((p[4]+p[5])+(p[6]+p[7])))
                      + (((p[8]+p[9])+(p[10]+p[11])) + ((p[12]+p[13])+(p[14]+p[15])));
            // ks=0 (k 0..15): dw0/dw2 from one swap, dw1/dw3 from the other
            unsigned d0 = cvtpk(p[0],  p[1]),  d2 = cvtpk(p[4],  p[5]);
            plswap(d0, d2);
            unsigned d1 = cvtpk(p[2],  p[3]),  d3 = cvtpk(p[6],  p[7]);
            plswap(d1, d3);
            pa[qb][0] = mk8(d0, d1, d2, d3);
            // ks=1 (k 16..31)
            unsigned e0 = cvtpk(p[8],  p[9]),  e2 = cvtpk(p[12], p[13]);
            plswap(e0, e2);
            unsigned e1 = cvtpk(p[10], p[11]), e3 = cvtpk(p[14], p[15]);
            plswap(e1, e3);
            pa[qb][1] = mk8(e0, e1, e2, e3);
        }

        // O += P V ; each V b-frag read once, reused by both qb
        #pragma unroll
        for (int ks = 0; ks < 2; ++ks) {
            #pragma unroll
            for (int db = 0; db < 2; ++db) {
                short8 bv = *(const short8*)&lv[swz(db * 32 + l32, khalf * 4 + ks * 2 + hi)];
                o[0][db] = __builtin_amdgcn_mfma_f32_32x32x16_bf16(pa[0][ks], bv, o[0][db], 0, 0, 0);
                o[1][db] = __builtin_amdgcn_mfma_f32_32x32x16_bf16(pa[1][ks], bv, o[1][db], 0, 0, 0);
            }
        }
    }

    // ---- combine k-half partials through LDS (tiles no longer needed) ----
    __syncthreads();                            // everyone done reading lk/lv
    float* sk = (float*)lk;                     // 2048 f32
    float* sv = (float*)lv;                     // 2048 f32
    const int idx = qw * 64 + lane;             // 0..255

    if (khalf == 1) { sk[idx] = lsum[0]; sk[256 + idx] = lsum[1]; }
    __syncthreads();
    if (khalf == 0) { lsum[0] += sk[idx]; lsum[1] += sk[256 + idx]; }

    #pragma unroll
    for (int qb = 0; qb < 2; ++qb) {
        #pragma unroll
        for (int db = 0; db < 2; ++db) {
            __syncthreads();                    // prior chunk (and lsum) reads done
            if (khalf == 1) {
                #pragma unroll
                for (int r = 0; r < 16; ++r) {
                    float* dst = (r < 8) ? sk : sv;
                    dst[(r & 7) * 256 + idx] = o[qb][db][r];
                }
            }
            __syncthreads();
            if (khalf == 0) {
                #pragma unroll
                for (int r = 0; r < 16; ++r) {
                    const float* src = (r < 8) ? sk : sv;
                    o[qb][db][r] += src[(r & 7) * 256 + idx];
                }
            }
        }
    }

    // ---- epilogue (k-half 0 waves): reduce lsum over hi halves, normalize, store ----
    if (khalf == 0) {
        #pragma unroll
        for (int qb = 0; qb < 2; ++qb) {
            float l = lsum[qb] + __shfl_xor(lsum[qb], 32, 64);  // row sum for q = qb*32+l32
            float inv = 1.0f / l;
            #pragma unroll
            for (int r = 0; r < 16; ++r) {
                const int qr = (r & 3) + 8 * (r >> 2) + 4 * hi;  // C/D row for this reg
                float invr = __shfl(inv, qr, 64);
                size_t row = (size_t)(b * Nn + qrow0 + qb * 32 + qr);
                #pragma unroll
                for (int db = 0; db < 2; ++db)
                    Yo[row * C1 + h * HD + db * 32 + l32] = __float2bfloat16(o[qb][db][r] * invr);
            }
        }
    }
}

extern "C" void kernel_launch(void* const* d_in, const int* in_sizes, int n_in,
                              void* d_out, int out_size, void* d_ws, size_t ws_size,
                              hipStream_t stream)
{
    const float* x1   = (const float*)d_in[0];
    const float* x2   = (const float*)d_in[1];
    const float* q1w  = (const float*)d_in[2];
    const float* q2w  = (const float*)d_in[3];
    const float* kv1w = (const float*)d_in[4];
    const float* kv2w = (const float*)d_in[5];
    const float* p1w  = (const float*)d_in[6];
    const float* p1b  = (const float*)d_in[7];
    const float* p2w  = (const float*)d_in[8];
    const float* p2b  = (const float*)d_in[9];
    float* out = (float*)d_out;

    bf16* ws = (bf16*)d_ws;
    size_t o = 0;
    bf16* x1b  = ws + o; o += (size_t)Mm * C1;
    bf16* x2b  = ws + o; o += (size_t)Mm * C2;
    bf16* wq1  = ws + o; o += C1 * C1;
    bf16* wq2  = ws + o; o += C1 * C2;
    bf16* wkv1 = ws + o; o += 2 * C1 * C2;
    bf16* wkv2 = ws + o; o += 2 * C1 * C1;
    bf16* wp1  = ws + o; o += C1 * C1;
    bf16* wp2  = ws + o; o += C1 * C1;
    bf16* Q1   = ws + o; o += (size_t)Mm * C1;
    bf16* K1   = ws + o; o += (size_t)Mm * C1;
    bf16* V1t  = ws + o; o += (size_t)Mm * C1;      // [B,H,64,N]
    bf16* Q2   = ws + o; o += (size_t)Mm * C1;
    bf16* K2   = ws + o; o += (size_t)Mm * C1;
    bf16* V2t  = ws + o; o += (size_t)Mm * C1;
    bf16* Y1   = ws + o; o += (size_t)Mm * C1;
    bf16* Y2   = ws + o; o += (size_t)Mm * C1;
    (void)ws_size; (void)in_sizes; (void)n_in; (void)out_size;

    // one convert launch for all 8 fp32->bf16 tensors
    CvtArgs ca;
    ca.s[0] = x1;   ca.d[0] = x1b;  int n0 = Mm * C1;
    ca.s[1] = x2;   ca.d[1] = x2b;  int n1 = Mm * C2;
    ca.s[2] = q1w;  ca.d[2] = wq1;  int n2 = C1 * C1;
    ca.s[3] = q2w;  ca.d[3] = wq2;  int n3 = C1 * C2;
    ca.s[4] = kv1w; ca.d[4] = wkv1; int n4 = 2 * C1 * C2;
    ca.s[5] = kv2w; ca.d[5] = wkv2; int n5 = 2 * C1 * C1;
    ca.s[6] = p1w;  ca.d[6] = wp1;  int n6 = C1 * C1;
    ca.s[7] = p2w;  ca.d[7] = wp2;  int n7 = C1 * C1;
    int ns[8] = {n0, n1, n2, n3, n4, n5, n6, n7};
    ca.off[0] = 0;
    for (int i = 0; i < 8; ++i) ca.off[i + 1] = ca.off[i] + ns[i];
    int total = ca.off[8];
    cvt_all<<<dim3((total / 4 + 255) / 256), 256, 0, stream>>>(ca);

    const float QS = 0.125f * 1.4426950408889634f;   // scale * log2(e), folded into Q

    // Q/KV projections
    gemm_bt<<<dim3(Mm / 64, C1 / 64), 256, 0, stream>>>(x1b, wq1, C1, 0, QS, Q1, nullptr, nullptr, nullptr, 0);
    gemm_bt<<<dim3(Mm / 64, (2 * C1) / 64), 256, 0, stream>>>(x2b, wkv1, C2, 1, 1.0f, K1, V1t, nullptr, nullptr, 0);
    gemm_bt<<<dim3(Mm / 64, C1 / 64), 256, 0, stream>>>(x2b, wq2, C2, 0, QS, Q2, nullptr, nullptr, nullptr, 0);
    gemm_bt<<<dim3(Mm / 64, (2 * C1) / 64), 256, 0, stream>>>(x1b, wkv2, C1, 1, 1.0f, K2, V2t, nullptr, nullptr, 0);

    // attention: 8-wave split-K blocks, 256 q-rows per block
    flash_kernel<<<dim3(Nn / 256, Hh, 2 * Bb), 512, 0, stream>>>(Q1, K1, V1t, Y1, Q2, K2, V2t, Y2);

    // output projections (fused bias + concat layout)
    gemm_bt<<<dim3(Mm / 64, C1 / 64), 256, 0, stream>>>(Y1, wp1, C1, 2, 1.0f, nullptr, nullptr, p1b, out, 0);
    gemm_bt<<<dim3(Mm / 64, C1 / 64), 256, 0, stream>>>(Y2, wp2, C1, 2, 1.0f, nullptr, nullptr, p2b, out, C1);
}

// Round 4
// 351.007 us; speedup vs baseline: 2.2702x; 2.2702x over previous
//
#include <hip/hip_runtime.h>
#include <hip/hip_bf16.h>

#define Bb 4
#define Nn 4096
#define C1 320
#define C2 256
#define Hh 5
#define HD 64
#define Mm (Bb*Nn)   // 16384

using bf16 = __hip_bfloat16;
typedef __attribute__((ext_vector_type(8))) short  short8;   // 8 bf16 = one MFMA A/B frag
typedef __attribute__((ext_vector_type(4))) short  short4_;
typedef __attribute__((ext_vector_type(4))) float  f32x4;    // 16x16 MFMA C/D frag

__device__ __forceinline__ short f2s(float f) {
    bf16 h = __float2bfloat16(f);
    short s;
    __builtin_memcpy(&s, &h, 2);
    return s;
}

__device__ __forceinline__ float fexp2(float x) {
#if __has_builtin(__builtin_amdgcn_exp2f)
    return __builtin_amdgcn_exp2f(x);
#else
    return exp2f(x);
#endif
}

// XOR-swizzled LDS tile addressing: 64-elem rows, 8 blocks of 8 bf16 (16B).
// physical elem offset of (row, logical block bb) = row*64 + (bb ^ (row&7))*8
__device__ __forceinline__ int swz(int row, int bb) {
    return row * 64 + ((bb ^ (row & 7)) << 3);
}

// ---------------- fp32 -> bf16 convert, all 8 tensors in one launch ----------------
struct CvtArgs {
    const float* s[8];
    bf16* d[8];
    int off[9];   // cumulative offsets, off[8] = total
};

__global__ void cvt_all(CvtArgs a) {
    int i = (blockIdx.x * blockDim.x + threadIdx.x) * 4;
    if (i >= a.off[8]) return;
    int seg = 0;
    #pragma unroll
    for (int k = 1; k < 8; ++k) seg += (i >= a.off[k]);
    int j = i - a.off[seg];
    float4 v = *(const float4*)(a.s[seg] + j);
    short4_ o = { f2s(v.x), f2s(v.y), f2s(v.z), f2s(v.w) };
    *(short4_*)(a.d[seg] + j) = o;
}

// ---------------- fused projection GEMM: 128x64 tile ----------------
// by < 5 : Q-part:  Qo[row*320+col] = bf16(acc * qs)          (W = Wq,  Nout=320)
// by >= 5: KV-part: col<320 -> Ko[row*320+col] = bf16(acc)    (W = Wkv, Nout=640)
//                   col>=320 -> Vo transposed [B,H,64,N]
// 4 waves; wave computes 32 m-rows x 64 n-cols (2 m-frags x 4 n-frags).
__global__ __launch_bounds__(256) void gemm_proj(
    const bf16* __restrict__ A, const bf16* __restrict__ Wq,
    const bf16* __restrict__ Wkv, int K, float qs,
    bf16* __restrict__ Qo, bf16* __restrict__ Ko, bf16* __restrict__ Vo)
{
    __shared__ bf16 la[128 * 64];
    __shared__ bf16 lw[64 * 64];
    const int m0 = blockIdx.x * 128;
    const bool isq = blockIdx.y < 5;
    const bf16* W = isq ? Wq : Wkv;
    const int n0 = (isq ? blockIdx.y : blockIdx.y - 5) * 64;
    const int t = threadIdx.x;
    const int wave = t >> 6, lane = t & 63, l16 = lane & 15, quad = lane >> 4;
    const int sr = t >> 3, sb = t & 7;      // sr 0..31, sb 0..7

    f32x4 acc[2][4];
    #pragma unroll
    for (int mf = 0; mf < 2; ++mf)
        #pragma unroll
        for (int nt = 0; nt < 4; ++nt) acc[mf][nt] = {0.f,0.f,0.f,0.f};

    const int nk = K >> 6;
    const bf16* ap = A + (size_t)(m0 + sr) * K + sb * 8;
    const bf16* wp = W + (size_t)(n0 + sr) * K + sb * 8;
    short8 ra0 = *(const short8*)ap;
    short8 ra1 = *(const short8*)(ap + (size_t)32 * K);
    short8 ra2 = *(const short8*)(ap + (size_t)64 * K);
    short8 ra3 = *(const short8*)(ap + (size_t)96 * K);
    short8 rw0 = *(const short8*)wp;
    short8 rw1 = *(const short8*)(wp + (size_t)32 * K);

    for (int kt = 0; kt < nk; ++kt) {
        __syncthreads();
        *(short8*)&la[swz(sr,      sb)] = ra0;
        *(short8*)&la[swz(sr + 32, sb)] = ra1;
        *(short8*)&la[swz(sr + 64, sb)] = ra2;
        *(short8*)&la[swz(sr + 96, sb)] = ra3;
        *(short8*)&lw[swz(sr,      sb)] = rw0;
        *(short8*)&lw[swz(sr + 32, sb)] = rw1;
        __syncthreads();
        if (kt + 1 < nk) {
            ap += 64; wp += 64;
            ra0 = *(const short8*)ap;
            ra1 = *(const short8*)(ap + (size_t)32 * K);
            ra2 = *(const short8*)(ap + (size_t)64 * K);
            ra3 = *(const short8*)(ap + (size_t)96 * K);
            rw0 = *(const short8*)wp;
            rw1 = *(const short8*)(wp + (size_t)32 * K);
        }
        const int arow = wave * 32 + l16;
        short8 a00 = *(const short8*)&la[swz(arow,      quad)];
        short8 a01 = *(const short8*)&la[swz(arow,      quad + 4)];
        short8 a10 = *(const short8*)&la[swz(arow + 16, quad)];
        short8 a11 = *(const short8*)&la[swz(arow + 16, quad + 4)];
        #pragma unroll
        for (int nt = 0; nt < 4; ++nt) {
            const int brow = nt * 16 + l16;
            short8 b0 = *(const short8*)&lw[swz(brow, quad)];
            short8 b1 = *(const short8*)&lw[swz(brow, quad + 4)];
            acc[0][nt] = __builtin_amdgcn_mfma_f32_16x16x32_bf16(a00, b0, acc[0][nt], 0, 0, 0);
            acc[0][nt] = __builtin_amdgcn_mfma_f32_16x16x32_bf16(a01, b1, acc[0][nt], 0, 0, 0);
            acc[1][nt] = __builtin_amdgcn_mfma_f32_16x16x32_bf16(a10, b0, acc[1][nt], 0, 0, 0);
            acc[1][nt] = __builtin_amdgcn_mfma_f32_16x16x32_bf16(a11, b1, acc[1][nt], 0, 0, 0);
        }
    }

    const bool isv = !isq && n0 >= C1;     // whole block is V-part or not
    #pragma unroll
    for (int mf = 0; mf < 2; ++mf) {
        const int mrow = m0 + wave * 32 + mf * 16 + quad * 4;
        if (isq) {
            #pragma unroll
            for (int nt = 0; nt < 4; ++nt) {
                int col = n0 + nt * 16 + l16;
                #pragma unroll
                for (int r = 0; r < 4; ++r)
                    Qo[(size_t)(mrow + r) * C1 + col] = __float2bfloat16(acc[mf][nt][r] * qs);
            }
        } else if (!isv) {
            #pragma unroll
            for (int nt = 0; nt < 4; ++nt) {
                int col = n0 + nt * 16 + l16;
                #pragma unroll
                for (int r = 0; r < 4; ++r)
                    Ko[(size_t)(mrow + r) * C1 + col] = __float2bfloat16(acc[mf][nt][r]);
            }
        } else {
            #pragma unroll
            for (int nt = 0; nt < 4; ++nt) {
                int col = n0 + nt * 16 + l16 - C1;
                int h = col >> 6, d = col & 63;
                #pragma unroll
                for (int r = 0; r < 4; ++r) {
                    int m = mrow + r;
                    int b = m >> 12, n = m & (Nn - 1);
                    Vo[((size_t)(b * Hh + h) * 64 + d) * Nn + n] = __float2bfloat16(acc[mf][nt][r]);
                }
            }
        }
    }
}

// ---------------- fused output projections: 128x64 tile, z = branch ----------------
// Of[row*640 + z*320 + col] = acc + bias[col]
__global__ __launch_bounds__(256) void gemm_out(
    const bf16* __restrict__ Y1, const bf16* __restrict__ Wp1, const float* __restrict__ B1,
    const bf16* __restrict__ Y2, const bf16* __restrict__ Wp2, const float* __restrict__ B2,
    float* __restrict__ Of)
{
    __shared__ bf16 la[128 * 64];
    __shared__ bf16 lw[64 * 64];
    const int zz = blockIdx.z;
    const bf16* A = zz ? Y2 : Y1;
    const bf16* W = zz ? Wp2 : Wp1;
    const float* bias = zz ? B2 : B1;
    const int ooff = zz ? C1 : 0;
    const int m0 = blockIdx.x * 128, n0 = blockIdx.y * 64;
    const int t = threadIdx.x;
    const int wave = t >> 6, lane = t & 63, l16 = lane & 15, quad = lane >> 4;
    const int sr = t >> 3, sb = t & 7;
    const int K = C1;

    f32x4 acc[2][4];
    #pragma unroll
    for (int mf = 0; mf < 2; ++mf)
        #pragma unroll
        for (int nt = 0; nt < 4; ++nt) acc[mf][nt] = {0.f,0.f,0.f,0.f};

    const int nk = K >> 6;
    const bf16* ap = A + (size_t)(m0 + sr) * K + sb * 8;
    const bf16* wp = W + (size_t)(n0 + sr) * K + sb * 8;
    short8 ra0 = *(const short8*)ap;
    short8 ra1 = *(const short8*)(ap + (size_t)32 * K);
    short8 ra2 = *(const short8*)(ap + (size_t)64 * K);
    short8 ra3 = *(const short8*)(ap + (size_t)96 * K);
    short8 rw0 = *(const short8*)wp;
    short8 rw1 = *(const short8*)(wp + (size_t)32 * K);

    for (int kt = 0; kt < nk; ++kt) {
        __syncthreads();
        *(short8*)&la[swz(sr,      sb)] = ra0;
        *(short8*)&la[swz(sr + 32, sb)] = ra1;
        *(short8*)&la[swz(sr + 64, sb)] = ra2;
        *(short8*)&la[swz(sr + 96, sb)] = ra3;
        *(short8*)&lw[swz(sr,      sb)] = rw0;
        *(short8*)&lw[swz(sr + 32, sb)] = rw1;
        __syncthreads();
        if (kt + 1 < nk) {
            ap += 64; wp += 64;
            ra0 = *(const short8*)ap;
            ra1 = *(const short8*)(ap + (size_t)32 * K);
            ra2 = *(const short8*)(ap + (size_t)64 * K);
            ra3 = *(const short8*)(ap + (size_t)96 * K);
            rw0 = *(const short8*)wp;
            rw1 = *(const short8*)(wp + (size_t)32 * K);
        }
        const int arow = wave * 32 + l16;
        short8 a00 = *(const short8*)&la[swz(arow,      quad)];
        short8 a01 = *(const short8*)&la[swz(arow,      quad + 4)];
        short8 a10 = *(const short8*)&la[swz(arow + 16, quad)];
        short8 a11 = *(const short8*)&la[swz(arow + 16, quad + 4)];
        #pragma unroll
        for (int nt = 0; nt < 4; ++nt) {
            const int brow = nt * 16 + l16;
            short8 b0 = *(const short8*)&lw[swz(brow, quad)];
            short8 b1 = *(const short8*)&lw[swz(brow, quad + 4)];
            acc[0][nt] = __builtin_amdgcn_mfma_f32_16x16x32_bf16(a00, b0, acc[0][nt], 0, 0, 0);
            acc[0][nt] = __builtin_amdgcn_mfma_f32_16x16x32_bf16(a01, b1, acc[0][nt], 0, 0, 0);
            acc[1][nt] = __builtin_amdgcn_mfma_f32_16x16x32_bf16(a10, b0, acc[1][nt], 0, 0, 0);
            acc[1][nt] = __builtin_amdgcn_mfma_f32_16x16x32_bf16(a11, b1, acc[1][nt], 0, 0, 0);
        }
    }

    #pragma unroll
    for (int mf = 0; mf < 2; ++mf) {
        const int mrow = m0 + wave * 32 + mf * 16 + quad * 4;
        #pragma unroll
        for (int nt = 0; nt < 4; ++nt) {
            int col = n0 + nt * 16 + l16;
            float bv = bias[col];
            #pragma unroll
            for (int r = 0; r < 4; ++r)
                Of[(size_t)(mrow + r) * 640 + ooff + col] = acc[mf][nt][r] + bv;
        }
    }
}

// ---------------- flash attention, both branches in one launch ----------------
// (proven R1 version, 196 us) 32x32 swapped-QK^T: block = 256 q-rows,
// 4 waves x 64 q (2 q-blocks of 32). S^T = mfma_32x32x16(K, Q): lane holds a
// full P-row slice (q = lane&31, k = (r&3)+8*(r>>2)+4*hi). P -> bf16 A-frags
// fully in-register (cvt_pk + permlane32_swap). K/V staged in 16KB swizzled
// LDS, register-prefetched one k-tile ahead, 2 barriers/kt. VALU lsum.
// Fixed m=0 softmax (Q pre-scaled by 0.125*log2e).
__device__ __forceinline__ unsigned cvtpk(float lo, float hi) {
    unsigned r;
    asm("v_cvt_pk_bf16_f32 %0, %1, %2" : "=v"(r) : "v"(lo), "v"(hi));
    return r;
}

__device__ __forceinline__ void plswap(unsigned &a, unsigned &b) {
#if __has_builtin(__builtin_amdgcn_permlane32_swap)
    auto r = __builtin_amdgcn_permlane32_swap(a, b, false, false);
    a = r[0]; b = r[1];
#else
    asm("v_permlane32_swap_b32 %0, %1" : "+v"(a), "+v"(b));
#endif
}

__device__ __forceinline__ short8 mk8(unsigned d0, unsigned d1, unsigned d2, unsigned d3) {
    union { unsigned u[4]; short8 s; } u;
    u.u[0] = d0; u.u[1] = d1; u.u[2] = d2; u.u[3] = d3;
    return u.s;
}

typedef __attribute__((ext_vector_type(16))) float f32x16;   // 32x32 MFMA C/D frag

__global__ __launch_bounds__(256, 2) void flash_kernel(
    const bf16* __restrict__ Q1, const bf16* __restrict__ K1,
    const bf16* __restrict__ V1, bf16* __restrict__ Y1,
    const bf16* __restrict__ Q2, const bf16* __restrict__ K2,
    const bf16* __restrict__ V2, bf16* __restrict__ Y2)
{
    __shared__ bf16 lk[64 * 64];        // K tile [k][d], swizzled
    __shared__ bf16 lv[64 * 64];        // V tile [d][k], swizzled (from pre-transposed Vt)
    const int qt = blockIdx.x, h = blockIdx.y, z = blockIdx.z;
    const int b = z & 3, branch = z >> 2;
    const bf16* Q  = branch ? Q2 : Q1;
    const bf16* Km = branch ? K2 : K1;
    const bf16* Vt = branch ? V2 : V1;
    bf16*       Yo = branch ? Y2 : Y1;

    const int t = threadIdx.x;
    const int wave = t >> 6, lane = t & 63;
    const int l32 = lane & 31, hi = lane >> 5;
    const int sr = t >> 3, sb = t & 7;

    const int qrow0 = qt * 256 + wave * 64;    // this wave's 64 q rows

    // Q B-frags for the whole loop: [qb][ksd] -> Q[qrow0+qb*32+l32][ksd*16+hi*8 ..+7]
    short8 qf[2][4];
    #pragma unroll
    for (int qb = 0; qb < 2; ++qb) {
        const bf16* qptr = Q + (size_t)(b * Nn + qrow0 + qb * 32 + l32) * C1 + h * HD + hi * 8;
        #pragma unroll
        for (int ksd = 0; ksd < 4; ++ksd)
            qf[qb][ksd] = *(const short8*)(qptr + ksd * 16);
    }

    f32x16 o[2][2];                    // [qb][db] PV accumulators
    #pragma unroll
    for (int qb = 0; qb < 2; ++qb)
        #pragma unroll
        for (int db = 0; db < 2; ++db)
            o[qb][db] = (f32x16){0.f,0.f,0.f,0.f,0.f,0.f,0.f,0.f,0.f,0.f,0.f,0.f,0.f,0.f,0.f,0.f};
    float lsum[2] = {0.f, 0.f};

    const bf16* Kbase = Km + (size_t)b * Nn * C1 + h * HD;
    const bf16* Vbase = Vt + (size_t)(b * Hh + h) * 64 * Nn;

    // register prefetch of the first k-tile staging data
    short8 rk0 = *(const short8*)(Kbase + (size_t)sr * C1 + sb * 8);
    short8 rk1 = *(const short8*)(Kbase + (size_t)(sr + 32) * C1 + sb * 8);
    short8 rv0 = *(const short8*)(Vbase + (size_t)sr * Nn + sb * 8);
    short8 rv1 = *(const short8*)(Vbase + (size_t)(sr + 32) * Nn + sb * 8);

    const int NT = Nn / 64;
    for (int kt = 0; kt < NT; ++kt) {
        __syncthreads();                         // prior iter's readers done
        *(short8*)&lk[swz(sr, sb)]      = rk0;
        *(short8*)&lk[swz(sr + 32, sb)] = rk1;
        *(short8*)&lv[swz(sr, sb)]      = rv0;
        *(short8*)&lv[swz(sr + 32, sb)] = rv1;
        __syncthreads();
        if (kt + 1 < NT) {                       // prefetch next tile; overlaps compute
            const int kn = (kt + 1) * 64;
            rk0 = *(const short8*)(Kbase + (size_t)(kn + sr) * C1 + sb * 8);
            rk1 = *(const short8*)(Kbase + (size_t)(kn + sr + 32) * C1 + sb * 8);
            rv0 = *(const short8*)(Vbase + (size_t)sr * Nn + kn + sb * 8);
            rv1 = *(const short8*)(Vbase + (size_t)(sr + 32) * Nn + kn + sb * 8);
        }

        #pragma unroll
        for (int kb = 0; kb < 2; ++kb) {
            // K a-frags (row k = kb*32 + l32, d = ksd*16 + hi*8), reused by both qb
            short8 ka[4];
            #pragma unroll
            for (int ksd = 0; ksd < 4; ++ksd)
                ka[ksd] = *(const short8*)&lk[swz(kb * 32 + l32, ksd * 2 + hi)];

            short8 pa[2][2];   // [qb][ks] PV A-frags, built fully in-register
            #pragma unroll
            for (int qb = 0; qb < 2; ++qb) {
                f32x16 s = (f32x16){0.f,0.f,0.f,0.f,0.f,0.f,0.f,0.f,0.f,0.f,0.f,0.f,0.f,0.f,0.f,0.f};
                #pragma unroll
                for (int ksd = 0; ksd < 4; ++ksd)
                    s = __builtin_amdgcn_mfma_f32_32x32x16_bf16(ka[ksd], qf[qb][ksd], s, 0, 0, 0);
                // p[r] = P[q = l32][k = (r&3) + 8*(r>>2) + 4*hi] (within this kb)
                float p[16];
                #pragma unroll
                for (int r = 0; r < 16; ++r) p[r] = fexp2(s[r]);
                lsum[qb] += (((p[0]+p[1])+(p[2]+p[3])) + ((p[4]+p[5])+(p[6]+p[7])))
                          + (((p[8]+p[9])+(p[10]+p[11])) + ((p[12]+p[13])+(p[14]+p[15])));
                // ks=0 (k 0..15): dw0/dw2 from one swap, dw1/dw3 from the other
                unsigned d0 = cvtpk(p[0],  p[1]),  d2 = cvtpk(p[4],  p[5]);
                plswap(d0, d2);
                unsigned d1 = cvtpk(p[2],  p[3]),  d3 = cvtpk(p[6],  p[7]);
                plswap(d1, d3);
                pa[qb][0] = mk8(d0, d1, d2, d3);
                // ks=1 (k 16..31)
                unsigned e0 = cvtpk(p[8],  p[9]),  e2 = cvtpk(p[12], p[13]);
                plswap(e0, e2);
                unsigned e1 = cvtpk(p[10], p[11]), e3 = cvtpk(p[14], p[15]);
                plswap(e1, e3);
                pa[qb][1] = mk8(e0, e1, e2, e3);
            }

            // O += P V ; each V b-frag read once, reused by both qb
            #pragma unroll
            for (int ks = 0; ks < 2; ++ks) {
                #pragma unroll
                for (int db = 0; db < 2; ++db) {
                    short8 bv = *(const short8*)&lv[swz(db * 32 + l32, kb * 4 + ks * 2 + hi)];
                    o[0][db] = __builtin_amdgcn_mfma_f32_32x32x16_bf16(pa[0][ks], bv, o[0][db], 0, 0, 0);
                    o[1][db] = __builtin_amdgcn_mfma_f32_32x32x16_bf16(pa[1][ks], bv, o[1][db], 0, 0, 0);
                }
            }
        }
    }

    // epilogue: complete row sums across hi halves, redistribute to C/D rows, store
    #pragma unroll
    for (int qb = 0; qb < 2; ++qb) {
        float l = lsum[qb] + __shfl_xor(lsum[qb], 32, 64);  // row sum for q = qb*32 + l32
        float inv = 1.0f / l;
        #pragma unroll
        for (int r = 0; r < 16; ++r) {
            const int qr = (r & 3) + 8 * (r >> 2) + 4 * hi;  // C/D row for this reg
            float invr = __shfl(inv, qr, 64);
            size_t row = (size_t)(b * Nn + qrow0 + qb * 32 + qr);
            #pragma unroll
            for (int db = 0; db < 2; ++db)
                Yo[row * C1 + h * HD + db * 32 + l32] = __float2bfloat16(o[qb][db][r] * invr);
        }
    }
}

extern "C" void kernel_launch(void* const* d_in, const int* in_sizes, int n_in,
                              void* d_out, int out_size, void* d_ws, size_t ws_size,
                              hipStream_t stream)
{
    const float* x1   = (const float*)d_in[0];
    const float* x2   = (const float*)d_in[1];
    const float* q1w  = (const float*)d_in[2];
    const float* q2w  = (const float*)d_in[3];
    const float* kv1w = (const float*)d_in[4];
    const float* kv2w = (const float*)d_in[5];
    const float* p1w  = (const float*)d_in[6];
    const float* p1b  = (const float*)d_in[7];
    const float* p2w  = (const float*)d_in[8];
    const float* p2b  = (const float*)d_in[9];
    float* out = (float*)d_out;

    bf16* ws = (bf16*)d_ws;
    size_t o = 0;
    bf16* x1b  = ws + o; o += (size_t)Mm * C1;
    bf16* x2b  = ws + o; o += (size_t)Mm * C2;
    bf16* wq1  = ws + o; o += C1 * C1;
    bf16* wq2  = ws + o; o += C1 * C2;
    bf16* wkv1 = ws + o; o += 2 * C1 * C2;
    bf16* wkv2 = ws + o; o += 2 * C1 * C1;
    bf16* wp1  = ws + o; o += C1 * C1;
    bf16* wp2  = ws + o; o += C1 * C1;
    bf16* Q1   = ws + o; o += (size_t)Mm * C1;
    bf16* K1   = ws + o; o += (size_t)Mm * C1;
    bf16* V1t  = ws + o; o += (size_t)Mm * C1;      // [B,H,64,N]
    bf16* Q2   = ws + o; o += (size_t)Mm * C1;
    bf16* K2   = ws + o; o += (size_t)Mm * C1;
    bf16* V2t  = ws + o; o += (size_t)Mm * C1;
    bf16* Y1   = ws + o; o += (size_t)Mm * C1;
    bf16* Y2   = ws + o; o += (size_t)Mm * C1;
    (void)ws_size; (void)in_sizes; (void)n_in; (void)out_size;

    // one convert launch for all 8 fp32->bf16 tensors
    CvtArgs ca;
    ca.s[0] = x1;   ca.d[0] = x1b;  int n0 = Mm * C1;
    ca.s[1] = x2;   ca.d[1] = x2b;  int n1 = Mm * C2;
    ca.s[2] = q1w;  ca.d[2] = wq1;  int n2 = C1 * C1;
    ca.s[3] = q2w;  ca.d[3] = wq2;  int n3 = C1 * C2;
    ca.s[4] = kv1w; ca.d[4] = wkv1; int n4 = 2 * C1 * C2;
    ca.s[5] = kv2w; ca.d[5] = wkv2; int n5 = 2 * C1 * C1;
    ca.s[6] = p1w;  ca.d[6] = wp1;  int n6 = C1 * C1;
    ca.s[7] = p2w;  ca.d[7] = wp2;  int n7 = C1 * C1;
    int ns[8] = {n0, n1, n2, n3, n4, n5, n6, n7};
    ca.off[0] = 0;
    for (int i = 0; i < 8; ++i) ca.off[i + 1] = ca.off[i] + ns[i];
    int total = ca.off[8];
    cvt_all<<<dim3((total / 4 + 255) / 256), 256, 0, stream>>>(ca);

    const float QS = 0.125f * 1.4426950408889634f;   // scale * log2(e), folded into Q

    // fused Q/KV projections: one launch per input tensor (grid 128 x 15)
    // x1b: q1 -> Q1 (K=320), kv2 -> K2,V2t (K=320)
    gemm_proj<<<dim3(Mm / 128, 15), 256, 0, stream>>>(x1b, wq1, wkv2, C1, QS, Q1, K2, V2t);
    // x2b: q2 -> Q2 (K=256), kv1 -> K1,V1t (K=256)
    gemm_proj<<<dim3(Mm / 128, 15), 256, 0, stream>>>(x2b, wq2, wkv1, C2, QS, Q2, K1, V1t);

    // attention, both branches in one launch; 256 q-rows per block (4 waves x 64 q)
    flash_kernel<<<dim3(Nn / 256, Hh, 2 * Bb), 256, 0, stream>>>(Q1, K1, V1t, Y1, Q2, K2, V2t, Y2);

    // fused output projections (bias + concat layout), z = branch
    gemm_out<<<dim3(Mm / 128, C1 / 64, 2), 256, 0, stream>>>(Y1, wp1, p1b, Y2, wp2, p2b, out);
}

// Round 5
// 348.235 us; speedup vs baseline: 2.2883x; 1.0080x over previous
//
#include <hip/hip_runtime.h>
#include <hip/hip_bf16.h>

#define Bb 4
#define Nn 4096
#define C1 320
#define C2 256
#define Hh 5
#define HD 64
#define Mm (Bb*Nn)   // 16384

using bf16 = __hip_bfloat16;
typedef __attribute__((ext_vector_type(8))) short  short8;   // 8 bf16 = one MFMA A/B frag
typedef __attribute__((ext_vector_type(4))) short  short4_;
typedef __attribute__((ext_vector_type(4))) float  f32x4;    // 16x16 MFMA C/D frag
typedef __attribute__((ext_vector_type(16))) float f32x16;   // 32x32 MFMA C/D frag

__device__ __forceinline__ short f2s(float f) {
    bf16 h = __float2bfloat16(f);
    short s;
    __builtin_memcpy(&s, &h, 2);
    return s;
}

__device__ __forceinline__ float fexp2(float x) {
#if __has_builtin(__builtin_amdgcn_exp2f)
    return __builtin_amdgcn_exp2f(x);
#else
    return exp2f(x);
#endif
}

// XOR-swizzled LDS tile addressing: 64-elem rows, 8 blocks of 8 bf16 (16B).
// physical elem offset of (row, logical block bb) = row*64 + (bb ^ (row&7))*8
__device__ __forceinline__ int swz(int row, int bb) {
    return row * 64 + ((bb ^ (row & 7)) << 3);
}

// pack two f32 -> one dword of 2 bf16 (src0 -> low half)
__device__ __forceinline__ unsigned cvtpk(float lo, float hi) {
    unsigned r;
    asm("v_cvt_pk_bf16_f32 %0, %1, %2" : "=v"(r) : "v"(lo), "v"(hi));
    return r;
}

// swap: a[lanes 32..63] <- b[lanes 0..31]; b[lanes 0..31] <- a[lanes 32..63]
__device__ __forceinline__ void plswap(unsigned &a, unsigned &b) {
#if __has_builtin(__builtin_amdgcn_permlane32_swap)
    auto r = __builtin_amdgcn_permlane32_swap(a, b, false, false);
    a = r[0]; b = r[1];
#else
    asm("v_permlane32_swap_b32 %0, %1" : "+v"(a), "+v"(b));
#endif
}

__device__ __forceinline__ short8 mk8(unsigned d0, unsigned d1, unsigned d2, unsigned d3) {
    union { unsigned u[4]; short8 s; } u;
    u.u[0] = d0; u.u[1] = d1; u.u[2] = d2; u.u[3] = d3;
    return u.s;
}

// ---------------- fp32 -> bf16 convert, all 8 tensors in one launch ----------------
struct CvtArgs {
    const float* s[8];
    bf16* d[8];
    int off[9];   // cumulative offsets, off[8] = total
};

__global__ void cvt_all(CvtArgs a) {
    int i = (blockIdx.x * blockDim.x + threadIdx.x) * 4;
    if (i >= a.off[8]) return;
    int seg = 0;
    #pragma unroll
    for (int k = 1; k < 8; ++k) seg += (i >= a.off[k]);
    int j = i - a.off[seg];
    float4 v = *(const float4*)(a.s[seg] + j);
    short4_ o = { f2s(v.x), f2s(v.y), f2s(v.z), f2s(v.w) };
    *(short4_*)(a.d[seg] + j) = o;
}

// ---------------- fused projection GEMM: 128x64 tile, both inputs in one launch --------
// by in [0,30): g = by/15 selects input set (0: x1-set K=320, 1: x2-set K=256), yy = by%15.
// yy < 5 : Q-part:  Qo[row*320+col] = bf16(acc * qs)          (W = Wq,  Nout=320)
// yy >= 5: KV-part: col<320 -> Ko[row*320+col] = bf16(acc)    (W = Wkv, Nout=640)
//                   col>=320 -> Vo transposed [B,H,64,N]
// 4 waves; wave computes 32 m-rows x 64 n-cols (2 m-frags x 4 n-frags).
__global__ __launch_bounds__(256) void gemm_proj(
    const bf16* __restrict__ A1, const bf16* __restrict__ Wq1, const bf16* __restrict__ Wkv1,
    const bf16* __restrict__ A2, const bf16* __restrict__ Wq2, const bf16* __restrict__ Wkv2,
    float qs,
    bf16* __restrict__ Qo1, bf16* __restrict__ Ko1, bf16* __restrict__ Vo1,
    bf16* __restrict__ Qo2, bf16* __restrict__ Ko2, bf16* __restrict__ Vo2)
{
    __shared__ bf16 la[128 * 64];
    __shared__ bf16 lw[64 * 64];
    const int m0 = blockIdx.x * 128;
    const int by = blockIdx.y;
    const int g = (by >= 15);
    const int yy = by - 15 * g;
    const int K = g ? C2 : C1;
    const bf16* A = g ? A2 : A1;
    const bool isq = yy < 5;
    const bf16* W = isq ? (g ? Wq2 : Wq1) : (g ? Wkv2 : Wkv1);
    bf16* Qo = g ? Qo2 : Qo1;
    bf16* Ko = g ? Ko2 : Ko1;
    bf16* Vo = g ? Vo2 : Vo1;
    const int n0 = (isq ? yy : yy - 5) * 64;
    const int t = threadIdx.x;
    const int wave = t >> 6, lane = t & 63, l16 = lane & 15, quad = lane >> 4;
    const int sr = t >> 3, sb = t & 7;      // sr 0..31, sb 0..7

    f32x4 acc[2][4];
    #pragma unroll
    for (int mf = 0; mf < 2; ++mf)
        #pragma unroll
        for (int nt = 0; nt < 4; ++nt) acc[mf][nt] = {0.f,0.f,0.f,0.f};

    const int nk = K >> 6;
    const bf16* ap = A + (size_t)(m0 + sr) * K + sb * 8;
    const bf16* wp = W + (size_t)(n0 + sr) * K + sb * 8;
    short8 ra0 = *(const short8*)ap;
    short8 ra1 = *(const short8*)(ap + (size_t)32 * K);
    short8 ra2 = *(const short8*)(ap + (size_t)64 * K);
    short8 ra3 = *(const short8*)(ap + (size_t)96 * K);
    short8 rw0 = *(const short8*)wp;
    short8 rw1 = *(const short8*)(wp + (size_t)32 * K);

    for (int kt = 0; kt < nk; ++kt) {
        __syncthreads();
        *(short8*)&la[swz(sr,      sb)] = ra0;
        *(short8*)&la[swz(sr + 32, sb)] = ra1;
        *(short8*)&la[swz(sr + 64, sb)] = ra2;
        *(short8*)&la[swz(sr + 96, sb)] = ra3;
        *(short8*)&lw[swz(sr,      sb)] = rw0;
        *(short8*)&lw[swz(sr + 32, sb)] = rw1;
        __syncthreads();
        if (kt + 1 < nk) {
            ap += 64; wp += 64;
            ra0 = *(const short8*)ap;
            ra1 = *(const short8*)(ap + (size_t)32 * K);
            ra2 = *(const short8*)(ap + (size_t)64 * K);
            ra3 = *(const short8*)(ap + (size_t)96 * K);
            rw0 = *(const short8*)wp;
            rw1 = *(const short8*)(wp + (size_t)32 * K);
        }
        const int arow = wave * 32 + l16;
        short8 a00 = *(const short8*)&la[swz(arow,      quad)];
        short8 a01 = *(const short8*)&la[swz(arow,      quad + 4)];
        short8 a10 = *(const short8*)&la[swz(arow + 16, quad)];
        short8 a11 = *(const short8*)&la[swz(arow + 16, quad + 4)];
        #pragma unroll
        for (int nt = 0; nt < 4; ++nt) {
            const int brow = nt * 16 + l16;
            short8 b0 = *(const short8*)&lw[swz(brow, quad)];
            short8 b1 = *(const short8*)&lw[swz(brow, quad + 4)];
            acc[0][nt] = __builtin_amdgcn_mfma_f32_16x16x32_bf16(a00, b0, acc[0][nt], 0, 0, 0);
            acc[0][nt] = __builtin_amdgcn_mfma_f32_16x16x32_bf16(a01, b1, acc[0][nt], 0, 0, 0);
            acc[1][nt] = __builtin_amdgcn_mfma_f32_16x16x32_bf16(a10, b0, acc[1][nt], 0, 0, 0);
            acc[1][nt] = __builtin_amdgcn_mfma_f32_16x16x32_bf16(a11, b1, acc[1][nt], 0, 0, 0);
        }
    }

    const bool isv = !isq && n0 >= C1;     // whole block is V-part or not
    #pragma unroll
    for (int mf = 0; mf < 2; ++mf) {
        const int mrow = m0 + wave * 32 + mf * 16 + quad * 4;
        if (isq) {
            #pragma unroll
            for (int nt = 0; nt < 4; ++nt) {
                int col = n0 + nt * 16 + l16;
                #pragma unroll
                for (int r = 0; r < 4; ++r)
                    Qo[(size_t)(mrow + r) * C1 + col] = __float2bfloat16(acc[mf][nt][r] * qs);
            }
        } else if (!isv) {
            #pragma unroll
            for (int nt = 0; nt < 4; ++nt) {
                int col = n0 + nt * 16 + l16;
                #pragma unroll
                for (int r = 0; r < 4; ++r)
                    Ko[(size_t)(mrow + r) * C1 + col] = __float2bfloat16(acc[mf][nt][r]);
            }
        } else {
            #pragma unroll
            for (int nt = 0; nt < 4; ++nt) {
                int col = n0 + nt * 16 + l16 - C1;
                int h = col >> 6, d = col & 63;
                #pragma unroll
                for (int r = 0; r < 4; ++r) {
                    int m = mrow + r;
                    int b = m >> 12, n = m & (Nn - 1);
                    Vo[((size_t)(b * Hh + h) * 64 + d) * Nn + n] = __float2bfloat16(acc[mf][nt][r]);
                }
            }
        }
    }
}

// ---------------- fused output projections: 128x64 tile, z = branch ----------------
// Of[row*640 + z*320 + col] = acc + bias[col]
__global__ __launch_bounds__(256) void gemm_out(
    const bf16* __restrict__ Y1, const bf16* __restrict__ Wp1, const float* __restrict__ B1,
    const bf16* __restrict__ Y2, const bf16* __restrict__ Wp2, const float* __restrict__ B2,
    float* __restrict__ Of)
{
    __shared__ bf16 la[128 * 64];
    __shared__ bf16 lw[64 * 64];
    const int zz = blockIdx.z;
    const bf16* A = zz ? Y2 : Y1;
    const bf16* W = zz ? Wp2 : Wp1;
    const float* bias = zz ? B2 : B1;
    const int ooff = zz ? C1 : 0;
    const int m0 = blockIdx.x * 128, n0 = blockIdx.y * 64;
    const int t = threadIdx.x;
    const int wave = t >> 6, lane = t & 63, l16 = lane & 15, quad = lane >> 4;
    const int sr = t >> 3, sb = t & 7;
    const int K = C1;

    f32x4 acc[2][4];
    #pragma unroll
    for (int mf = 0; mf < 2; ++mf)
        #pragma unroll
        for (int nt = 0; nt < 4; ++nt) acc[mf][nt] = {0.f,0.f,0.f,0.f};

    const int nk = K >> 6;
    const bf16* ap = A + (size_t)(m0 + sr) * K + sb * 8;
    const bf16* wp = W + (size_t)(n0 + sr) * K + sb * 8;
    short8 ra0 = *(const short8*)ap;
    short8 ra1 = *(const short8*)(ap + (size_t)32 * K);
    short8 ra2 = *(const short8*)(ap + (size_t)64 * K);
    short8 ra3 = *(const short8*)(ap + (size_t)96 * K);
    short8 rw0 = *(const short8*)wp;
    short8 rw1 = *(const short8*)(wp + (size_t)32 * K);

    for (int kt = 0; kt < nk; ++kt) {
        __syncthreads();
        *(short8*)&la[swz(sr,      sb)] = ra0;
        *(short8*)&la[swz(sr + 32, sb)] = ra1;
        *(short8*)&la[swz(sr + 64, sb)] = ra2;
        *(short8*)&la[swz(sr + 96, sb)] = ra3;
        *(short8*)&lw[swz(sr,      sb)] = rw0;
        *(short8*)&lw[swz(sr + 32, sb)] = rw1;
        __syncthreads();
        if (kt + 1 < nk) {
            ap += 64; wp += 64;
            ra0 = *(const short8*)ap;
            ra1 = *(const short8*)(ap + (size_t)32 * K);
            ra2 = *(const short8*)(ap + (size_t)64 * K);
            ra3 = *(const short8*)(ap + (size_t)96 * K);
            rw0 = *(const short8*)wp;
            rw1 = *(const short8*)(wp + (size_t)32 * K);
        }
        const int arow = wave * 32 + l16;
        short8 a00 = *(const short8*)&la[swz(arow,      quad)];
        short8 a01 = *(const short8*)&la[swz(arow,      quad + 4)];
        short8 a10 = *(const short8*)&la[swz(arow + 16, quad)];
        short8 a11 = *(const short8*)&la[swz(arow + 16, quad + 4)];
        #pragma unroll
        for (int nt = 0; nt < 4; ++nt) {
            const int brow = nt * 16 + l16;
            short8 b0 = *(const short8*)&lw[swz(brow, quad)];
            short8 b1 = *(const short8*)&lw[swz(brow, quad + 4)];
            acc[0][nt] = __builtin_amdgcn_mfma_f32_16x16x32_bf16(a00, b0, acc[0][nt], 0, 0, 0);
            acc[0][nt] = __builtin_amdgcn_mfma_f32_16x16x32_bf16(a01, b1, acc[0][nt], 0, 0, 0);
            acc[1][nt] = __builtin_amdgcn_mfma_f32_16x16x32_bf16(a10, b0, acc[1][nt], 0, 0, 0);
            acc[1][nt] = __builtin_amdgcn_mfma_f32_16x16x32_bf16(a11, b1, acc[1][nt], 0, 0, 0);
        }
    }

    #pragma unroll
    for (int mf = 0; mf < 2; ++mf) {
        const int mrow = m0 + wave * 32 + mf * 16 + quad * 4;
        #pragma unroll
        for (int nt = 0; nt < 4; ++nt) {
            int col = n0 + nt * 16 + l16;
            float bv = bias[col];
            #pragma unroll
            for (int r = 0; r < 4; ++r)
                Of[(size_t)(mrow + r) * 640 + ooff + col] = acc[mf][nt][r] + bv;
        }
    }
}

// ---------------- flash attention, both branches in one launch ----------------
// Per-wave structure = proven R1 version (swapped QK^T 32x32, in-register P via
// cvt_pk + permlane32_swap, VALU lsum, fixed m=0 softmax, Q pre-scaled).
// CHANGE vs R1: 2-wave blocks (128 q-rows) -> grid = 32x5x8 = 1280 blocks =
// exactly 5.0 blocks/CU, eliminating the 640-block round-quantization idle
// (2.5 blocks/CU => wall = 3 rounds for 2.5 rounds of work, ~17% lost).
// Staging: 128 threads each stage 4 K-rows + 4 V-rows (register-prefetched
// one k-tile ahead), 16KB swizzled LDS, 2 cheap 2-wave barriers per kt.
__global__ __launch_bounds__(128, 2) void flash_kernel(
    const bf16* __restrict__ Q1, const bf16* __restrict__ K1,
    const bf16* __restrict__ V1, bf16* __restrict__ Y1,
    const bf16* __restrict__ Q2, const bf16* __restrict__ K2,
    const bf16* __restrict__ V2, bf16* __restrict__ Y2)
{
    __shared__ bf16 lk[64 * 64];        // K tile [k][d], swizzled
    __shared__ bf16 lv[64 * 64];        // V tile [d][k], swizzled (from pre-transposed Vt)
    const int qt = blockIdx.x, h = blockIdx.y, z = blockIdx.z;
    const int b = z & 3, branch = z >> 2;
    const bf16* Q  = branch ? Q2 : Q1;
    const bf16* Km = branch ? K2 : K1;
    const bf16* Vt = branch ? V2 : V1;
    bf16*       Yo = branch ? Y2 : Y1;

    const int t = threadIdx.x;
    const int wave = t >> 6, lane = t & 63;
    const int l32 = lane & 31, hi = lane >> 5;
    const int sr = t >> 3, sb = t & 7;          // sr 0..15, sb 0..7

    const int qrow0 = qt * 128 + wave * 64;     // this wave's 64 q rows

    // Q B-frags for the whole loop: [qb][ksd] -> Q[qrow0+qb*32+l32][ksd*16+hi*8 ..+7]
    short8 qf[2][4];
    #pragma unroll
    for (int qb = 0; qb < 2; ++qb) {
        const bf16* qptr = Q + (size_t)(b * Nn + qrow0 + qb * 32 + l32) * C1 + h * HD + hi * 8;
        #pragma unroll
        for (int ksd = 0; ksd < 4; ++ksd)
            qf[qb][ksd] = *(const short8*)(qptr + ksd * 16);
    }

    f32x16 o[2][2];                    // [qb][db] PV accumulators
    #pragma unroll
    for (int qb = 0; qb < 2; ++qb)
        #pragma unroll
        for (int db = 0; db < 2; ++db)
            o[qb][db] = (f32x16){0.f,0.f,0.f,0.f,0.f,0.f,0.f,0.f,0.f,0.f,0.f,0.f,0.f,0.f,0.f,0.f};
    float lsum[2] = {0.f, 0.f};

    const bf16* Kbase = Km + (size_t)b * Nn * C1 + h * HD;
    const bf16* Vbase = Vt + (size_t)(b * Hh + h) * 64 * Nn;

    // register prefetch of the first k-tile staging data: 4 K rows + 4 V rows/thread
    const bf16* kp[4];
    const bf16* vp[4];
    short8 rk[4], rv[4];
    #pragma unroll
    for (int i = 0; i < 4; ++i) {
        kp[i] = Kbase + (size_t)(sr + 16 * i) * C1 + sb * 8;
        vp[i] = Vbase + (size_t)(sr + 16 * i) * Nn + sb * 8;
        rk[i] = *(const short8*)kp[i];
        rv[i] = *(const short8*)vp[i];
    }

    const int NT = Nn / 64;
    for (int kt = 0; kt < NT; ++kt) {
        __syncthreads();                         // prior iter's readers done
        #pragma unroll
        for (int i = 0; i < 4; ++i) {
            *(short8*)&lk[swz(sr + 16 * i, sb)] = rk[i];
            *(short8*)&lv[swz(sr + 16 * i, sb)] = rv[i];
        }
        __syncthreads();
        if (kt + 1 < NT) {                       // prefetch next tile; overlaps compute
            #pragma unroll
            for (int i = 0; i < 4; ++i) {
                kp[i] += 64 * C1; vp[i] += 64;
                rk[i] = *(const short8*)kp[i];
                rv[i] = *(const short8*)vp[i];
            }
        }

        #pragma unroll
        for (int kb = 0; kb < 2; ++kb) {
            // K a-frags (row k = kb*32 + l32, d = ksd*16 + hi*8), reused by both qb
            short8 ka[4];
            #pragma unroll
            for (int ksd = 0; ksd < 4; ++ksd)
                ka[ksd] = *(const short8*)&lk[swz(kb * 32 + l32, ksd * 2 + hi)];

            short8 pa[2][2];   // [qb][ks] PV A-frags, built fully in-register
            #pragma unroll
            for (int qb = 0; qb < 2; ++qb) {
                f32x16 s = (f32x16){0.f,0.f,0.f,0.f,0.f,0.f,0.f,0.f,0.f,0.f,0.f,0.f,0.f,0.f,0.f,0.f};
                #pragma unroll
                for (int ksd = 0; ksd < 4; ++ksd)
                    s = __builtin_amdgcn_mfma_f32_32x32x16_bf16(ka[ksd], qf[qb][ksd], s, 0, 0, 0);
                // p[r] = P[q = l32][k = (r&3) + 8*(r>>2) + 4*hi] (within this kb)
                float p[16];
                #pragma unroll
                for (int r = 0; r < 16; ++r) p[r] = fexp2(s[r]);
                lsum[qb] += (((p[0]+p[1])+(p[2]+p[3])) + ((p[4]+p[5])+(p[6]+p[7])))
                          + (((p[8]+p[9])+(p[10]+p[11])) + ((p[12]+p[13])+(p[14]+p[15])));
                // ks=0 (k 0..15): dw0/dw2 from one swap, dw1/dw3 from the other
                unsigned d0 = cvtpk(p[0],  p[1]),  d2 = cvtpk(p[4],  p[5]);
                plswap(d0, d2);
                unsigned d1 = cvtpk(p[2],  p[3]),  d3 = cvtpk(p[6],  p[7]);
                plswap(d1, d3);
                pa[qb][0] = mk8(d0, d1, d2, d3);
                // ks=1 (k 16..31)
                unsigned e0 = cvtpk(p[8],  p[9]),  e2 = cvtpk(p[12], p[13]);
                plswap(e0, e2);
                unsigned e1 = cvtpk(p[10], p[11]), e3 = cvtpk(p[14], p[15]);
                plswap(e1, e3);
                pa[qb][1] = mk8(e0, e1, e2, e3);
            }

            // O += P V ; each V b-frag read once, reused by both qb
            #pragma unroll
            for (int ks = 0; ks < 2; ++ks) {
                #pragma unroll
                for (int db = 0; db < 2; ++db) {
                    short8 bv = *(const short8*)&lv[swz(db * 32 + l32, kb * 4 + ks * 2 + hi)];
                    o[0][db] = __builtin_amdgcn_mfma_f32_32x32x16_bf16(pa[0][ks], bv, o[0][db], 0, 0, 0);
                    o[1][db] = __builtin_amdgcn_mfma_f32_32x32x16_bf16(pa[1][ks], bv, o[1][db], 0, 0, 0);
                }
            }
        }
    }

    // epilogue: complete row sums across hi halves, redistribute to C/D rows, store
    #pragma unroll
    for (int qb = 0; qb < 2; ++qb) {
        float l = lsum[qb] + __shfl_xor(lsum[qb], 32, 64);  // row sum for q = qb*32 + l32
        float inv = 1.0f / l;
        #pragma unroll
        for (int r = 0; r < 16; ++r) {
            const int qr = (r & 3) + 8 * (r >> 2) + 4 * hi;  // C/D row for this reg
            float invr = __shfl(inv, qr, 64);
            size_t row = (size_t)(b * Nn + qrow0 + qb * 32 + qr);
            #pragma unroll
            for (int db = 0; db < 2; ++db)
                Yo[row * C1 + h * HD + db * 32 + l32] = __float2bfloat16(o[qb][db][r] * invr);
        }
    }
}

extern "C" void kernel_launch(void* const* d_in, const int* in_sizes, int n_in,
                              void* d_out, int out_size, void* d_ws, size_t ws_size,
                              hipStream_t stream)
{
    const float* x1   = (const float*)d_in[0];
    const float* x2   = (const float*)d_in[1];
    const float* q1w  = (const float*)d_in[2];
    const float* q2w  = (const float*)d_in[3];
    const float* kv1w = (const float*)d_in[4];
    const float* kv2w = (const float*)d_in[5];
    const float* p1w  = (const float*)d_in[6];
    const float* p1b  = (const float*)d_in[7];
    const float* p2w  = (const float*)d_in[8];
    const float* p2b  = (const float*)d_in[9];
    float* out = (float*)d_out;

    bf16* ws = (bf16*)d_ws;
    size_t o = 0;
    bf16* x1b  = ws + o; o += (size_t)Mm * C1;
    bf16* x2b  = ws + o; o += (size_t)Mm * C2;
    bf16* wq1  = ws + o; o += C1 * C1;
    bf16* wq2  = ws + o; o += C1 * C2;
    bf16* wkv1 = ws + o; o += 2 * C1 * C2;
    bf16* wkv2 = ws + o; o += 2 * C1 * C1;
    bf16* wp1  = ws + o; o += C1 * C1;
    bf16* wp2  = ws + o; o += C1 * C1;
    bf16* Q1   = ws + o; o += (size_t)Mm * C1;
    bf16* K1   = ws + o; o += (size_t)Mm * C1;
    bf16* V1t  = ws + o; o += (size_t)Mm * C1;      // [B,H,64,N]
    bf16* Q2   = ws + o; o += (size_t)Mm * C1;
    bf16* K2   = ws + o; o += (size_t)Mm * C1;
    bf16* V2t  = ws + o; o += (size_t)Mm * C1;
    bf16* Y1   = ws + o; o += (size_t)Mm * C1;
    bf16* Y2   = ws + o; o += (size_t)Mm * C1;
    (void)ws_size; (void)in_sizes; (void)n_in; (void)out_size;

    // one convert launch for all 8 fp32->bf16 tensors
    CvtArgs ca;
    ca.s[0] = x1;   ca.d[0] = x1b;  int n0 = Mm * C1;
    ca.s[1] = x2;   ca.d[1] = x2b;  int n1 = Mm * C2;
    ca.s[2] = q1w;  ca.d[2] = wq1;  int n2 = C1 * C1;
    ca.s[3] = q2w;  ca.d[3] = wq2;  int n3 = C1 * C2;
    ca.s[4] = kv1w; ca.d[4] = wkv1; int n4 = 2 * C1 * C2;
    ca.s[5] = kv2w; ca.d[5] = wkv2; int n5 = 2 * C1 * C1;
    ca.s[6] = p1w;  ca.d[6] = wp1;  int n6 = C1 * C1;
    ca.s[7] = p2w;  ca.d[7] = wp2;  int n7 = C1 * C1;
    int ns[8] = {n0, n1, n2, n3, n4, n5, n6, n7};
    ca.off[0] = 0;
    for (int i = 0; i < 8; ++i) ca.off[i + 1] = ca.off[i] + ns[i];
    int total = ca.off[8];
    cvt_all<<<dim3((total / 4 + 255) / 256), 256, 0, stream>>>(ca);

    const float QS = 0.125f * 1.4426950408889634f;   // scale * log2(e), folded into Q

    // fused Q/KV projections: both input tensors in ONE launch (grid 128 x 30)
    // set0 (by 0-14):  x1b, K=320: q1 -> Q1, kv2 -> K2,V2t
    // set1 (by 15-29): x2b, K=256: q2 -> Q2, kv1 -> K1,V1t
    gemm_proj<<<dim3(Mm / 128, 30), 256, 0, stream>>>(
        x1b, wq1, wkv2, x2b, wq2, wkv1, QS,
        Q1, K2, V2t, Q2, K1, V1t);

    // attention, both branches in one launch; 128 q-rows per block (2 waves x 64 q),
    // grid = 32 x 5 x 8 = 1280 blocks = exactly 5 blocks/CU
    flash_kernel<<<dim3(Nn / 128, Hh, 2 * Bb), 128, 0, stream>>>(Q1, K1, V1t, Y1, Q2, K2, V2t, Y2);

    // fused output projections (bias + concat layout), z = branch
    gemm_out<<<dim3(Mm / 128, C1 / 64, 2), 256, 0, stream>>>(Y1, wp1, p1b, Y2, wp2, p2b, out);
}